// Round 12
// baseline (342.707 us; speedup 1.0000x reference)
//
#include <hip/hip_runtime.h>
#include <hip/hip_bf16.h>

#define N_NODES 50000
#define N_EDGES 400000
#define N_ETOT  (N_EDGES + N_NODES)
#define NHEADS  4
#define SCAN_BLOCKS 196   // cdiv(N_NODES, 256)

static constexpr float NEG_SLOPE = 0.2f;
static constexpr float EPS_ = 1e-16f;
static constexpr float NEG_BIG = -1e30f;   // NaN-free empty-segment sentinel

typedef __attribute__((ext_vector_type(8))) short bf16x8;
typedef __attribute__((ext_vector_type(4))) float f32x4;

__device__ __forceinline__ float b2f(__hip_bfloat16 v) { return __bfloat162float(v); }
__device__ __forceinline__ float ldf(const void* p, long i, int isbf) {
    return isbf ? b2f(((const __hip_bfloat16*)p)[i]) : ((const float*)p)[i];
}
__device__ __forceinline__ void unpack8(int4 v, float* f) {
    const unsigned* u = (const unsigned*)&v;
#pragma unroll
    for (int i = 0; i < 4; ++i) {
        f[2 * i]     = __uint_as_float(u[i] << 16);
        f[2 * i + 1] = __uint_as_float(u[i] & 0xffff0000u);
    }
}
__device__ __forceinline__ void unpack4(int2 v, float* f) {
    const unsigned* u = (const unsigned*)&v;
    f[0] = __uint_as_float(u[0] << 16);
    f[1] = __uint_as_float(u[0] & 0xffff0000u);
    f[2] = __uint_as_float(u[1] << 16);
    f[3] = __uint_as_float(u[1] & 0xffff0000u);
}

// ---------------- dtype detector + counts zeroing (fused) ----------------
__global__ __launch_bounds__(256)
void detect_zero_kernel(const void* __restrict__ x, int* __restrict__ flag,
                        int* __restrict__ counts)
{
    const int idx = blockIdx.x * 256 + threadIdx.x;
    if (idx < N_NODES) counts[idx] = 0;
    if (blockIdx.x != 0) return;
    __shared__ int cnt;
    if (threadIdx.x == 0) cnt = 0;
    __syncthreads();
    int local = 0;
    const __hip_bfloat16* p = (const __hip_bfloat16*)x;
    for (int i = threadIdx.x; i < 4096; i += 256) {
        float v = b2f(p[2 * i]);
        if (!(fabsf(v) < 64.f)) local++;
    }
    atomicAdd(&cnt, local);
    __syncthreads();
    if (threadIdx.x == 0) *flag = (cnt < 64) ? 1 : 0;
}

// ---------------- weight prep: transpose all 6 W to [c][64] bf16 panels ----------------
__global__ __launch_bounds__(256)
void prep_w_kernel(const void* __restrict__ Wl0, const void* __restrict__ Wr0,
                   const void* __restrict__ Wl1, const void* __restrict__ Wr1,
                   const void* __restrict__ Wl2, const void* __restrict__ Wr2,
                   __hip_bfloat16* __restrict__ wt, const int* __restrict__ flagp)
{
    const int isbf = *flagp;
    int idx = blockIdx.x * 256 + threadIdx.x;   // 0..49151
    const void* W; int dout, obase;
    if      (idx <  4096) { W = Wl0; dout = 64;  obase = 0; }
    else if (idx <  8192) { W = Wr0; dout = 64;  obase = 4096;  idx -= 4096; }
    else if (idx < 12288) { W = Wl1; dout = 64;  obase = 8192;  idx -= 8192; }
    else if (idx < 16384) { W = Wr1; dout = 64;  obase = 12288; idx -= 12288; }
    else if (idx < 32768) { W = Wl2; dout = 256; obase = 16384; idx -= 16384; }
    else                  { W = Wr2; dout = 256; obase = 32768; idx -= 32768; }
    const int k = idx / dout, c = idx % dout;
    wt[obase + c * 64 + k] = __float2bfloat16(ldf(W, idx, isbf));
}

// ---------------- CSR build ----------------
__global__ __launch_bounds__(256)
void count_kernel(const int* __restrict__ ei, int* __restrict__ counts)
{
    const int e = blockIdx.x * 256 + threadIdx.x;
    if (e >= N_ETOT) return;
    const int d = (e < N_EDGES) ? ei[N_EDGES + e] : e - N_EDGES;
    atomicAdd(&counts[d], 1);
}

__global__ __launch_bounds__(256)
void scan_phase1(const int* __restrict__ counts, int* __restrict__ bsum)
{
    __shared__ int sh[256];
    const int idx = blockIdx.x * 256 + threadIdx.x;
    sh[threadIdx.x] = (idx < N_NODES) ? counts[idx] : 0;
    __syncthreads();
    for (int off = 128; off > 0; off >>= 1) {
        if (threadIdx.x < off) sh[threadIdx.x] += sh[threadIdx.x + off];
        __syncthreads();
    }
    if (threadIdx.x == 0) bsum[blockIdx.x] = sh[0];
}

__global__ __launch_bounds__(256)
void scan_phase2(const int* __restrict__ bsum, int* __restrict__ bpre, int* __restrict__ offs)
{
    __shared__ int sh[256];
    const int t = threadIdx.x;
    const int v = (t < SCAN_BLOCKS) ? bsum[t] : 0;
    sh[t] = v;
    __syncthreads();
    for (int off = 1; off < 256; off <<= 1) {
        int u = (t >= off) ? sh[t - off] : 0;
        __syncthreads();
        sh[t] += u;
        __syncthreads();
    }
    if (t < SCAN_BLOCKS) bpre[t] = sh[t] - v;
    if (t == 0) offs[N_NODES] = N_ETOT;
}

__global__ __launch_bounds__(256)
void scan_phase3(int* __restrict__ counts, const int* __restrict__ bpre,
                 int* __restrict__ offs)
{
    __shared__ int sh[256];
    const int t = threadIdx.x;
    const int idx = blockIdx.x * 256 + t;
    const int v = (idx < N_NODES) ? counts[idx] : 0;
    sh[t] = v;
    __syncthreads();
    for (int off = 1; off < 256; off <<= 1) {
        int u = (t >= off) ? sh[t - off] : 0;
        __syncthreads();
        sh[t] += u;
        __syncthreads();
    }
    if (idx < N_NODES) {
        const int o = bpre[blockIdx.x] + sh[t] - v;
        offs[idx] = o;
        counts[idx] = o;      // counts becomes the fill cursor
    }
}

__global__ __launch_bounds__(256)
void fill_kernel(const int* __restrict__ ei, int* __restrict__ cursor,
                 int* __restrict__ csr_src)
{
    const int e = blockIdx.x * 256 + threadIdx.x;
    if (e >= N_ETOT) return;
    int s, d;
    if (e < N_EDGES) { s = ei[e]; d = ei[N_EDGES + e]; } else { s = d = e - N_EDGES; }
    const int pos = atomicAdd(&cursor[d], 1);
    csr_src[pos] = s;
}

// ---------------- MFMA linear (proven R10) ----------------
template<int NCHUNK, bool EXT>
__global__ __launch_bounds__(256)
void lin_mfma_kernel(const void* __restrict__ hin, const __hip_bfloat16* __restrict__ wt,
                     int offL, int offR,
                     const void* __restrict__ bL, const void* __restrict__ bR,
                     __hip_bfloat16* __restrict__ outL, __hip_bfloat16* __restrict__ outR,
                     const int* __restrict__ flagp)
{
    constexpr int LD = NCHUNK * 64;
    const int isbf = *flagp;
    const int side  = blockIdx.y & 1;
    const int chunk = blockIdx.y >> 1;
    const __hip_bfloat16* wpanel = wt + (side ? offR : offL);
    const void* bb = side ? bR : bL;
    __hip_bfloat16* outp = side ? outR : outL;

    const int lane = threadIdx.x & 63;
    const int w = threadIdx.x >> 6;
    const int r0 = blockIdx.x * 64 + w * 16;
    const int arow = r0 + (lane & 15);
    const int kb = (lane >> 4) * 8;

    bf16x8 a0 = {}, a1 = {};
    if (arow < N_NODES) {
        if (EXT && !isbf) {
            const float* pf = (const float*)hin + (long)arow * 64;
            short t0[8], t1[8];
#pragma unroll
            for (int j = 0; j < 8; ++j) {
                __hip_bfloat16 h0 = __float2bfloat16(pf[kb + j]);
                __hip_bfloat16 h1 = __float2bfloat16(pf[32 + kb + j]);
                t0[j] = *(short*)&h0; t1[j] = *(short*)&h1;
            }
            a0 = *(const bf16x8*)t0; a1 = *(const bf16x8*)t1;
        } else {
            const __hip_bfloat16* pb = (const __hip_bfloat16*)hin + (long)arow * 64;
            a0 = *(const bf16x8*)(pb + kb);
            a1 = *(const bf16x8*)(pb + 32 + kb);
        }
    }

    f32x4 acc[4];
#pragma unroll
    for (int ct = 0; ct < 4; ++ct) {
        const __hip_bfloat16* wc = wpanel + (long)(chunk * 64 + ct * 16 + (lane & 15)) * 64 + kb;
        const bf16x8 b0 = *(const bf16x8*)wc;
        const bf16x8 b1 = *(const bf16x8*)(wc + 32);
        f32x4 z = {0.f, 0.f, 0.f, 0.f};
        z = __builtin_amdgcn_mfma_f32_16x16x32_bf16(a0, b0, z, 0, 0, 0);
        acc[ct] = __builtin_amdgcn_mfma_f32_16x16x32_bf16(a1, b1, z, 0, 0, 0);
    }

    const int crow0 = r0 + (lane >> 4) * 4;
#pragma unroll
    for (int ct = 0; ct < 4; ++ct) {
        const int col = chunk * 64 + ct * 16 + (lane & 15);
        const float bv = ldf(bb, col, isbf);
#pragma unroll
        for (int reg = 0; reg < 4; ++reg) {
            const int row = crow0 + reg;
            if (row < N_NODES)
                outp[(long)row * LD + col] = __float2bfloat16(acc[ct][reg] + bv);
        }
    }
}

// ---------------- fused attention, layers 0/1 (R10 proven): 16 lanes/edge --------------
__global__ __launch_bounds__(256)
void gat_fused16_kernel(const int* __restrict__ csr_src, const int* __restrict__ offsets,
                        const __hip_bfloat16* __restrict__ xl, const __hip_bfloat16* __restrict__ xr,
                        const void* __restrict__ att, const void* __restrict__ bias,
                        __hip_bfloat16* __restrict__ hout, const int* __restrict__ flagp)
{
    const int isbf = *flagp;
    const int node = blockIdx.x * 4 + (threadIdx.x >> 6);
    if (node >= N_NODES) return;
    const int lane = threadIdx.x & 63;
    const int l16 = lane & 15;            // channels l16*4 .. +4 (head = l16>>2)
    const int q = lane >> 4;              // quarter handles edges p ≡ q (mod 4)
    float a[4], xrv[4];
    {
        const int2 v = *(const int2*)(xr + (long)node * 64 + l16 * 4);
        unpack4(v, xrv);
#pragma unroll
        for (int j = 0; j < 4; ++j) a[j] = ldf(att, l16 * 4 + j, isbf);
    }
    const int beg = offsets[node], end = offsets[node + 1];
    float m = NEG_BIG, s = 0.f, acc[4] = {0.f, 0.f, 0.f, 0.f};
    for (int p = beg + q; p < end; p += 4) {
        const int src = csr_src[p];
        const int2 v = *(const int2*)(xl + (long)src * 64 + l16 * 4);
        float xlv[4]; unpack4(v, xlv);
        float t = 0.f;
#pragma unroll
        for (int j = 0; j < 4; ++j) {
            float u = xlv[j] + xrv[j];
            u = u > 0.f ? u : NEG_SLOPE * u;
            t += u * a[j];
        }
        t += __shfl_xor(t, 1); t += __shfl_xor(t, 2);   // 16-ch head dot (4 lanes)
        const float mn = fmaxf(m, t);
        const float sc = __expf(m - mn);
        const float w  = __expf(t - mn);
        s = s * sc + w;
#pragma unroll
        for (int j = 0; j < 4; ++j) acc[j] = acc[j] * sc + w * xlv[j];
        m = mn;
    }
    // merge 4 quarter-states (NaN-free via NEG_BIG sentinel)
#pragma unroll
    for (int step = 16; step <= 32; step <<= 1) {
        const float m_p = __shfl_xor(m, step);
        const float s_p = __shfl_xor(s, step);
        const float mm = fmaxf(m, m_p);
        const float e0 = __expf(m - mm), e1 = __expf(m_p - mm);
        s = s * e0 + s_p * e1;
#pragma unroll
        for (int j = 0; j < 4; ++j) {
            const float ap = __shfl_xor(acc[j], step);
            acc[j] = acc[j] * e0 + ap * e1;
        }
        m = mm;
    }
    if (q == 0) {
        __hip_bfloat16 ob[4];
#pragma unroll
        for (int j = 0; j < 4; ++j) {
            float o = acc[j] / (s + EPS_) + ldf(bias, l16 * 4 + j, isbf);
            o = o > 0.f ? o : (__expf(o) - 1.f);   // ELU
            ob[j] = __float2bfloat16(o);
        }
        *(int2*)(hout + (long)node * 64 + l16 * 4) = *(int2*)ob;
    }
}

// ---------------- layer 2: 16 lanes/edge (16 ch each), 4 edges/wave/iter ----------------
// lane = g*16 + l16: group g handles edges p ≡ g (mod 4); lane covers channels l16*16..+16.
// head = l16>>2; head-dot reduce = shfl 1,2 (4 lanes); head-mean = shfl 4,8 butterfly.
__global__ __launch_bounds__(256)
void gat256_kernel(const int* __restrict__ csr_src, const int* __restrict__ offsets,
                   const __hip_bfloat16* __restrict__ xl2, const __hip_bfloat16* __restrict__ xr2,
                   const void* __restrict__ att, const void* __restrict__ bias,
                   void* __restrict__ out, const int* __restrict__ flagp)
{
    const int isbf = *flagp;
    const int node = blockIdx.x * 4 + (threadIdx.x >> 6);
    if (node >= N_NODES) return;
    const int lane = threadIdx.x & 63;
    const int l16 = lane & 15;
    const int g = lane >> 4;
    const int c0 = l16 * 16;
    float a[16], xrv[16];
    {
        const int4 v0 = *(const int4*)(xr2 + (long)node * 256 + c0);
        const int4 v1 = *(const int4*)(xr2 + (long)node * 256 + c0 + 8);
        unpack8(v0, xrv); unpack8(v1, xrv + 8);
#pragma unroll
        for (int j = 0; j < 16; ++j) a[j] = ldf(att, c0 + j, isbf);
    }
    const int beg = offsets[node], end = offsets[node + 1];
    float m = NEG_BIG, s = 0.f;
    float acc[16];
#pragma unroll
    for (int j = 0; j < 16; ++j) acc[j] = 0.f;
    for (int p = beg + g; p < end; p += 4) {
        const int src = csr_src[p];
        const int4 v0 = *(const int4*)(xl2 + (long)src * 256 + c0);
        const int4 v1 = *(const int4*)(xl2 + (long)src * 256 + c0 + 8);
        float xlv[16]; unpack8(v0, xlv); unpack8(v1, xlv + 8);
        float t = 0.f;
#pragma unroll
        for (int j = 0; j < 16; ++j) {
            float u = xlv[j] + xrv[j];
            u = u > 0.f ? u : NEG_SLOPE * u;
            t += u * a[j];
        }
        t += __shfl_xor(t, 1); t += __shfl_xor(t, 2);   // 64-ch head dot (4 lanes x 16ch)
        const float mn = fmaxf(m, t);
        const float sc = __expf(m - mn);
        const float w  = __expf(t - mn);
        s = s * sc + w;
#pragma unroll
        for (int j = 0; j < 16; ++j) acc[j] = acc[j] * sc + w * xlv[j];
        m = mn;
    }
    // merge 4 group-states (NaN-free)
#pragma unroll
    for (int step = 16; step <= 32; step <<= 1) {
        const float m_p = __shfl_xor(m, step);
        const float s_p = __shfl_xor(s, step);
        const float mm = fmaxf(m, m_p);
        const float e0 = __expf(m - mm), e1 = __expf(m_p - mm);
        s = s * e0 + s_p * e1;
#pragma unroll
        for (int j = 0; j < 16; ++j) {
            const float ap = __shfl_xor(acc[j], step);
            acc[j] = acc[j] * e0 + ap * e1;
        }
        m = mm;
    }
    const float inv = 1.f / (s + EPS_);
#pragma unroll
    for (int j = 0; j < 16; ++j) acc[j] *= inv;
    // head mean: butterfly over head bits (2,3) of l16; within-head block (l16&3) preserved
#pragma unroll
    for (int j = 0; j < 16; ++j) {
        acc[j] += __shfl_xor(acc[j], 4);
        acc[j] += __shfl_xor(acc[j], 8);
        acc[j] *= 0.25f;
    }
    if (lane < 4) {                       // g==0, l16<4: channels l16*16 .. +16
        const int cb = lane * 16;
        if (isbf) {
            __hip_bfloat16 ob[16];
#pragma unroll
            for (int j = 0; j < 16; ++j)
                ob[j] = __float2bfloat16(acc[j] + ldf(bias, cb + j, isbf));
            __hip_bfloat16* po = (__hip_bfloat16*)out + (long)node * 64 + cb;
            *(int4*)po       = *(const int4*)ob;
            *(int4*)(po + 8) = *(const int4*)(ob + 8);
        } else {
            float* po = (float*)out + (long)node * 64 + cb;
#pragma unroll
            for (int j = 0; j < 16; ++j) po[j] = acc[j] + ldf(bias, cb + j, isbf);
        }
    }
}

static inline int cdiv(int a, int b) { return (a + b - 1) / b; }

extern "C" void kernel_launch(void* const* d_in, const int* in_sizes, int n_in,
                              void* d_out, int out_size, void* d_ws, size_t ws_size,
                              hipStream_t stream)
{
    const void* x   = d_in[0];
    const int*  ei  = (const int*)d_in[1];
    const void* Wl0 = d_in[2];  const void* bl0 = d_in[3];
    const void* Wr0 = d_in[4];  const void* br0 = d_in[5];
    const void* att0  = d_in[6];  const void* bias0 = d_in[7];
    const void* Wl1 = d_in[8];  const void* bl1 = d_in[9];
    const void* Wr1 = d_in[10]; const void* br1 = d_in[11];
    const void* att1  = d_in[12]; const void* bias1 = d_in[13];
    const void* Wl2 = d_in[14]; const void* bl2 = d_in[15];
    const void* Wr2 = d_in[16]; const void* br2 = d_in[17];
    const void* att2  = d_in[18]; const void* bias2 = d_in[19];

    // workspace layout (~59.9 MB), f32-slot offsets
    float* ws = (float*)d_ws;
    __hip_bfloat16* hbuf = (__hip_bfloat16*)ws;                  // [N,64] bf16
    __hip_bfloat16* xl2  = (__hip_bfloat16*)(ws + 1600000);      // [N,256] bf16
    __hip_bfloat16* xr2  = (__hip_bfloat16*)(ws + 8000000);      // [N,256] bf16
    __hip_bfloat16* xl   = xl2;                                  // [N,64] alias (layers 0/1)
    __hip_bfloat16* xr   = (__hip_bfloat16*)(ws + 4800000);      // [N,64] alias
    int* csr    = (int*)(ws + 14400000);                         // 450k
    int* offs   = csr + 450000;                                  // 50001
    int* counts = offs + 50004;                                  // 50k (doubles as fill cursor)
    int* bsum   = counts + 50000;
    int* bpre   = bsum + 256;
    int* flag   = bpre + 256;
    __hip_bfloat16* wt = (__hip_bfloat16*)(flag + 4);            // 49152 bf16 panels (96 KB)

    const int NGE = cdiv(N_ETOT, 256);
    const int NGW = cdiv(N_NODES, 4);
    const int NGM = cdiv(N_NODES, 64);

    // ---- prep: dtype flag + counts zero, weight transpose ----
    detect_zero_kernel<<<SCAN_BLOCKS, 256, 0, stream>>>(x, flag, counts);
    prep_w_kernel<<<192, 256, 0, stream>>>(Wl0, Wr0, Wl1, Wr1, Wl2, Wr2, wt, flag);

    // ---- CSR build ----
    count_kernel<<<NGE, 256, 0, stream>>>(ei, counts);
    scan_phase1<<<SCAN_BLOCKS, 256, 0, stream>>>(counts, bsum);
    scan_phase2<<<1, 256, 0, stream>>>(bsum, bpre, offs);
    scan_phase3<<<SCAN_BLOCKS, 256, 0, stream>>>(counts, bpre, offs);
    fill_kernel<<<NGE, 256, 0, stream>>>(ei, counts, csr);

    // ---- layer 0 ----
    lin_mfma_kernel<1, true><<<dim3(NGM, 2), 256, 0, stream>>>(
        x, wt, 0, 4096, bl0, br0, xl, xr, flag);
    gat_fused16_kernel<<<NGW, 256, 0, stream>>>(csr, offs, xl, xr, att0, bias0, hbuf, flag);

    // ---- layer 1 ----
    lin_mfma_kernel<1, false><<<dim3(NGM, 2), 256, 0, stream>>>(
        hbuf, wt, 8192, 12288, bl1, br1, xl, xr, flag);
    gat_fused16_kernel<<<NGW, 256, 0, stream>>>(csr, offs, xl, xr, att1, bias1, hbuf, flag);

    // ---- layer 2: MFMA linear, then one all-heads pass ----
    lin_mfma_kernel<4, false><<<dim3(NGM, 8), 256, 0, stream>>>(
        hbuf, wt, 16384, 32768, bl2, br2, xl2, xr2, flag);
    gat256_kernel<<<NGW, 256, 0, stream>>>(csr, offs, xl2, xr2, att2, bias2, d_out, flag);
}

// Round 13
// 274.696 us; speedup vs baseline: 1.2476x; 1.2476x over previous
//
#include <hip/hip_runtime.h>
#include <hip/hip_bf16.h>

#define N_NODES 50000
#define N_EDGES 400000
#define N_ETOT  (N_EDGES + N_NODES)
#define NHEADS  4
#define SCAN_BLOCKS 196   // cdiv(N_NODES, 256)

static constexpr float NEG_SLOPE = 0.2f;
static constexpr float EPS_ = 1e-16f;
static constexpr float NEG_BIG = -1e30f;   // NaN-free empty-segment sentinel

typedef __attribute__((ext_vector_type(8))) short bf16x8;
typedef __attribute__((ext_vector_type(4))) float f32x4;

__device__ __forceinline__ float b2f(__hip_bfloat16 v) { return __bfloat162float(v); }
__device__ __forceinline__ float ldf(const void* p, long i, int isbf) {
    return isbf ? b2f(((const __hip_bfloat16*)p)[i]) : ((const float*)p)[i];
}
__device__ __forceinline__ void unpack8(int4 v, float* f) {
    const unsigned* u = (const unsigned*)&v;
#pragma unroll
    for (int i = 0; i < 4; ++i) {
        f[2 * i]     = __uint_as_float(u[i] << 16);
        f[2 * i + 1] = __uint_as_float(u[i] & 0xffff0000u);
    }
}
__device__ __forceinline__ void unpack4(int2 v, float* f) {
    const unsigned* u = (const unsigned*)&v;
    f[0] = __uint_as_float(u[0] << 16);
    f[1] = __uint_as_float(u[0] & 0xffff0000u);
    f[2] = __uint_as_float(u[1] << 16);
    f[3] = __uint_as_float(u[1] & 0xffff0000u);
}

// ---------------- dtype detector + counts zeroing (fused) ----------------
__global__ __launch_bounds__(256)
void detect_zero_kernel(const void* __restrict__ x, int* __restrict__ flag,
                        int* __restrict__ counts)
{
    const int idx = blockIdx.x * 256 + threadIdx.x;
    if (idx < N_NODES) counts[idx] = 0;
    if (blockIdx.x != 0) return;
    __shared__ int cnt;
    if (threadIdx.x == 0) cnt = 0;
    __syncthreads();
    int local = 0;
    const __hip_bfloat16* p = (const __hip_bfloat16*)x;
    for (int i = threadIdx.x; i < 4096; i += 256) {
        float v = b2f(p[2 * i]);
        if (!(fabsf(v) < 64.f)) local++;
    }
    atomicAdd(&cnt, local);
    __syncthreads();
    if (threadIdx.x == 0) *flag = (cnt < 64) ? 1 : 0;
}

// ---------------- weight prep: transpose all 6 W to [c][64] bf16 panels ----------------
__global__ __launch_bounds__(256)
void prep_w_kernel(const void* __restrict__ Wl0, const void* __restrict__ Wr0,
                   const void* __restrict__ Wl1, const void* __restrict__ Wr1,
                   const void* __restrict__ Wl2, const void* __restrict__ Wr2,
                   __hip_bfloat16* __restrict__ wt, const int* __restrict__ flagp)
{
    const int isbf = *flagp;
    int idx = blockIdx.x * 256 + threadIdx.x;   // 0..49151
    const void* W; int dout, obase;
    if      (idx <  4096) { W = Wl0; dout = 64;  obase = 0; }
    else if (idx <  8192) { W = Wr0; dout = 64;  obase = 4096;  idx -= 4096; }
    else if (idx < 12288) { W = Wl1; dout = 64;  obase = 8192;  idx -= 8192; }
    else if (idx < 16384) { W = Wr1; dout = 64;  obase = 12288; idx -= 12288; }
    else if (idx < 32768) { W = Wl2; dout = 256; obase = 16384; idx -= 16384; }
    else                  { W = Wr2; dout = 256; obase = 32768; idx -= 32768; }
    const int k = idx / dout, c = idx % dout;
    wt[obase + c * 64 + k] = __float2bfloat16(ldf(W, idx, isbf));
}

// ---------------- CSR build ----------------
__global__ __launch_bounds__(256)
void count_kernel(const int* __restrict__ ei, int* __restrict__ counts)
{
    const int e = blockIdx.x * 256 + threadIdx.x;
    if (e >= N_ETOT) return;
    const int d = (e < N_EDGES) ? ei[N_EDGES + e] : e - N_EDGES;
    atomicAdd(&counts[d], 1);
}

__global__ __launch_bounds__(256)
void scan_phase1(const int* __restrict__ counts, int* __restrict__ bsum)
{
    __shared__ int sh[256];
    const int idx = blockIdx.x * 256 + threadIdx.x;
    sh[threadIdx.x] = (idx < N_NODES) ? counts[idx] : 0;
    __syncthreads();
    for (int off = 128; off > 0; off >>= 1) {
        if (threadIdx.x < off) sh[threadIdx.x] += sh[threadIdx.x + off];
        __syncthreads();
    }
    if (threadIdx.x == 0) bsum[blockIdx.x] = sh[0];
}

__global__ __launch_bounds__(256)
void scan_phase2(const int* __restrict__ bsum, int* __restrict__ bpre, int* __restrict__ offs)
{
    __shared__ int sh[256];
    const int t = threadIdx.x;
    const int v = (t < SCAN_BLOCKS) ? bsum[t] : 0;
    sh[t] = v;
    __syncthreads();
    for (int off = 1; off < 256; off <<= 1) {
        int u = (t >= off) ? sh[t - off] : 0;
        __syncthreads();
        sh[t] += u;
        __syncthreads();
    }
    if (t < SCAN_BLOCKS) bpre[t] = sh[t] - v;
    if (t == 0) offs[N_NODES] = N_ETOT;
}

__global__ __launch_bounds__(256)
void scan_phase3(int* __restrict__ counts, const int* __restrict__ bpre,
                 int* __restrict__ offs)
{
    __shared__ int sh[256];
    const int t = threadIdx.x;
    const int idx = blockIdx.x * 256 + t;
    const int v = (idx < N_NODES) ? counts[idx] : 0;
    sh[t] = v;
    __syncthreads();
    for (int off = 1; off < 256; off <<= 1) {
        int u = (t >= off) ? sh[t - off] : 0;
        __syncthreads();
        sh[t] += u;
        __syncthreads();
    }
    if (idx < N_NODES) {
        const int o = bpre[blockIdx.x] + sh[t] - v;
        offs[idx] = o;
        counts[idx] = o;      // counts becomes the fill cursor
    }
}

__global__ __launch_bounds__(256)
void fill_kernel(const int* __restrict__ ei, int* __restrict__ cursor,
                 int* __restrict__ csr_src)
{
    const int e = blockIdx.x * 256 + threadIdx.x;
    if (e >= N_ETOT) return;
    int s, d;
    if (e < N_EDGES) { s = ei[e]; d = ei[N_EDGES + e]; } else { s = d = e - N_EDGES; }
    const int pos = atomicAdd(&cursor[d], 1);
    csr_src[pos] = s;
}

// ---------------- MFMA linear (proven R10) ----------------
template<int NCHUNK, bool EXT>
__global__ __launch_bounds__(256)
void lin_mfma_kernel(const void* __restrict__ hin, const __hip_bfloat16* __restrict__ wt,
                     int offL, int offR,
                     const void* __restrict__ bL, const void* __restrict__ bR,
                     __hip_bfloat16* __restrict__ outL, __hip_bfloat16* __restrict__ outR,
                     const int* __restrict__ flagp)
{
    constexpr int LD = NCHUNK * 64;
    const int isbf = *flagp;
    const int side  = blockIdx.y & 1;
    const int chunk = blockIdx.y >> 1;
    const __hip_bfloat16* wpanel = wt + (side ? offR : offL);
    const void* bb = side ? bR : bL;
    __hip_bfloat16* outp = side ? outR : outL;

    const int lane = threadIdx.x & 63;
    const int w = threadIdx.x >> 6;
    const int r0 = blockIdx.x * 64 + w * 16;
    const int arow = r0 + (lane & 15);
    const int kb = (lane >> 4) * 8;

    bf16x8 a0 = {}, a1 = {};
    if (arow < N_NODES) {
        if (EXT && !isbf) {
            const float* pf = (const float*)hin + (long)arow * 64;
            short t0[8], t1[8];
#pragma unroll
            for (int j = 0; j < 8; ++j) {
                __hip_bfloat16 h0 = __float2bfloat16(pf[kb + j]);
                __hip_bfloat16 h1 = __float2bfloat16(pf[32 + kb + j]);
                t0[j] = *(short*)&h0; t1[j] = *(short*)&h1;
            }
            a0 = *(const bf16x8*)t0; a1 = *(const bf16x8*)t1;
        } else {
            const __hip_bfloat16* pb = (const __hip_bfloat16*)hin + (long)arow * 64;
            a0 = *(const bf16x8*)(pb + kb);
            a1 = *(const bf16x8*)(pb + 32 + kb);
        }
    }

    f32x4 acc[4];
#pragma unroll
    for (int ct = 0; ct < 4; ++ct) {
        const __hip_bfloat16* wc = wpanel + (long)(chunk * 64 + ct * 16 + (lane & 15)) * 64 + kb;
        const bf16x8 b0 = *(const bf16x8*)wc;
        const bf16x8 b1 = *(const bf16x8*)(wc + 32);
        f32x4 z = {0.f, 0.f, 0.f, 0.f};
        z = __builtin_amdgcn_mfma_f32_16x16x32_bf16(a0, b0, z, 0, 0, 0);
        acc[ct] = __builtin_amdgcn_mfma_f32_16x16x32_bf16(a1, b1, z, 0, 0, 0);
    }

    const int crow0 = r0 + (lane >> 4) * 4;
#pragma unroll
    for (int ct = 0; ct < 4; ++ct) {
        const int col = chunk * 64 + ct * 16 + (lane & 15);
        const float bv = ldf(bb, col, isbf);
#pragma unroll
        for (int reg = 0; reg < 4; ++reg) {
            const int row = crow0 + reg;
            if (row < N_NODES)
                outp[(long)row * LD + col] = __float2bfloat16(acc[ct][reg] + bv);
        }
    }
}

// ---------------- fused attention, layers 0/1: 16 lanes/edge + 2-stage prefetch --------
__global__ __launch_bounds__(256)
void gat_fused16_kernel(const int* __restrict__ csr_src, const int* __restrict__ offsets,
                        const __hip_bfloat16* __restrict__ xl, const __hip_bfloat16* __restrict__ xr,
                        const void* __restrict__ att, const void* __restrict__ bias,
                        __hip_bfloat16* __restrict__ hout, const int* __restrict__ flagp)
{
    const int isbf = *flagp;
    const int node = blockIdx.x * 4 + (threadIdx.x >> 6);
    if (node >= N_NODES) return;
    const int lane = threadIdx.x & 63;
    const int l16 = lane & 15;            // channels l16*4 .. +4 (head = l16>>2)
    const int q = lane >> 4;              // quarter handles edges p ≡ q (mod 4)
    float a[4], xrv[4];
    {
        const int2 v = *(const int2*)(xr + (long)node * 64 + l16 * 4);
        unpack4(v, xrv);
#pragma unroll
        for (int j = 0; j < 4; ++j) a[j] = ldf(att, l16 * 4 + j, isbf);
    }
    const int beg = offsets[node], end = offsets[node + 1];
    float m = NEG_BIG, s = 0.f, acc[4] = {0.f, 0.f, 0.f, 0.f};
    int p = beg + q;
    if (p < end) {
        // 2-stage pipeline: row p in v_cur; index for p+4 in src_nxt
        int2 v_cur = *(const int2*)(xl + (long)csr_src[p] * 64 + l16 * 4);
        int pn = p + 4 < end ? p + 4 : p;
        int src_nxt = csr_src[pn];
        for (; p < end; p += 4) {
            const int2 v_nxt = *(const int2*)(xl + (long)src_nxt * 64 + l16 * 4); // in flight
            const int p2 = p + 8 < end ? p + 8 : p;
            src_nxt = csr_src[p2];                                                // in flight
            float xlv[4]; unpack4(v_cur, xlv);
            float t = 0.f;
#pragma unroll
            for (int j = 0; j < 4; ++j) {
                float u = xlv[j] + xrv[j];
                u = u > 0.f ? u : NEG_SLOPE * u;
                t += u * a[j];
            }
            t += __shfl_xor(t, 1); t += __shfl_xor(t, 2);   // 16-ch head dot (4 lanes)
            const float mn = fmaxf(m, t);
            const float sc = __expf(m - mn);
            const float w  = __expf(t - mn);
            s = s * sc + w;
#pragma unroll
            for (int j = 0; j < 4; ++j) acc[j] = acc[j] * sc + w * xlv[j];
            m = mn;
            v_cur = v_nxt;
        }
    }
    // merge 4 quarter-states (NaN-free via NEG_BIG sentinel)
#pragma unroll
    for (int step = 16; step <= 32; step <<= 1) {
        const float m_p = __shfl_xor(m, step);
        const float s_p = __shfl_xor(s, step);
        const float mm = fmaxf(m, m_p);
        const float e0 = __expf(m - mm), e1 = __expf(m_p - mm);
        s = s * e0 + s_p * e1;
#pragma unroll
        for (int j = 0; j < 4; ++j) {
            const float ap = __shfl_xor(acc[j], step);
            acc[j] = acc[j] * e0 + ap * e1;
        }
        m = mm;
    }
    if (q == 0) {
        __hip_bfloat16 ob[4];
#pragma unroll
        for (int j = 0; j < 4; ++j) {
            float o = acc[j] / (s + EPS_) + ldf(bias, l16 * 4 + j, isbf);
            o = o > 0.f ? o : (__expf(o) - 1.f);   // ELU
            ob[j] = __float2bfloat16(o);
        }
        *(int2*)(hout + (long)node * 64 + l16 * 4) = *(int2*)ob;
    }
}

// ---------------- layer 2 (R10 form): half-wave/edge, 8 ch/lane + 2-stage prefetch ------
__global__ __launch_bounds__(256)
void gat256_kernel(const int* __restrict__ csr_src, const int* __restrict__ offsets,
                   const __hip_bfloat16* __restrict__ xl2, const __hip_bfloat16* __restrict__ xr2,
                   const void* __restrict__ att, const void* __restrict__ bias,
                   void* __restrict__ out, const int* __restrict__ flagp)
{
    const int isbf = *flagp;
    const int node = blockIdx.x * 4 + (threadIdx.x >> 6);
    if (node >= N_NODES) return;
    const int lane = threadIdx.x & 63;
    const int l32 = lane & 31;            // channels l32*8 .. +8 (head = l32>>3)
    const int half = lane >> 5;
    float a[8], xrv[8];
    {
        const int4 v = *(const int4*)(xr2 + (long)node * 256 + l32 * 8);
        unpack8(v, xrv);
#pragma unroll
        for (int j = 0; j < 8; ++j) a[j] = ldf(att, l32 * 8 + j, isbf);
    }
    const int beg = offsets[node], end = offsets[node + 1];
    float m = NEG_BIG, s = 0.f;
    float acc[8] = {0.f, 0.f, 0.f, 0.f, 0.f, 0.f, 0.f, 0.f};
    int p = beg + half;
    if (p < end) {
        // 2-stage pipeline: row p in v_cur; index for p+2 in src_nxt
        int4 v_cur = *(const int4*)(xl2 + (long)csr_src[p] * 256 + l32 * 8);
        int pn = p + 2 < end ? p + 2 : p;
        int src_nxt = csr_src[pn];
        for (; p < end; p += 2) {
            const int4 v_nxt = *(const int4*)(xl2 + (long)src_nxt * 256 + l32 * 8); // in flight
            const int p2 = p + 4 < end ? p + 4 : p;
            src_nxt = csr_src[p2];                                                  // in flight
            float xlv[8]; unpack8(v_cur, xlv);
            float t = 0.f;
#pragma unroll
            for (int j = 0; j < 8; ++j) {
                float u = xlv[j] + xrv[j];
                u = u > 0.f ? u : NEG_SLOPE * u;
                t += u * a[j];
            }
            t += __shfl_xor(t, 1); t += __shfl_xor(t, 2); t += __shfl_xor(t, 4);
            const float mn = fmaxf(m, t);
            const float sc = __expf(m - mn);
            const float w  = __expf(t - mn);
            s = s * sc + w;
#pragma unroll
            for (int j = 0; j < 8; ++j) acc[j] = acc[j] * sc + w * xlv[j];
            m = mn;
            v_cur = v_nxt;
        }
    }
    // merge the two half-wave states
    {
        const float m_p = __shfl_xor(m, 32);
        const float s_p = __shfl_xor(s, 32);
        const float mm = fmaxf(m, m_p);
        const float e0 = __expf(m - mm), e1 = __expf(m_p - mm);
        s = s * e0 + s_p * e1;
#pragma unroll
        for (int j = 0; j < 8; ++j) {
            const float ap = __shfl_xor(acc[j], 32);
            acc[j] = acc[j] * e0 + ap * e1;
        }
    }
    const float inv = 1.f / (s + EPS_);
#pragma unroll
    for (int j = 0; j < 8; ++j) acc[j] *= inv;
    // head mean: butterfly over head bits (3,4) of l32
#pragma unroll
    for (int j = 0; j < 8; ++j) {
        acc[j] += __shfl_xor(acc[j], 8);
        acc[j] += __shfl_xor(acc[j], 16);
        acc[j] *= 0.25f;
    }
    if (lane < 8) {
        const int c0 = lane * 8;
        if (isbf) {
            __hip_bfloat16 ob[8];
#pragma unroll
            for (int j = 0; j < 8; ++j)
                ob[j] = __float2bfloat16(acc[j] + ldf(bias, c0 + j, isbf));
            *(int4*)((__hip_bfloat16*)out + (long)node * 64 + c0) = *(const int4*)ob;
        } else {
            float* po = (float*)out + (long)node * 64 + c0;
#pragma unroll
            for (int j = 0; j < 8; ++j) po[j] = acc[j] + ldf(bias, c0 + j, isbf);
        }
    }
}

static inline int cdiv(int a, int b) { return (a + b - 1) / b; }

extern "C" void kernel_launch(void* const* d_in, const int* in_sizes, int n_in,
                              void* d_out, int out_size, void* d_ws, size_t ws_size,
                              hipStream_t stream)
{
    const void* x   = d_in[0];
    const int*  ei  = (const int*)d_in[1];
    const void* Wl0 = d_in[2];  const void* bl0 = d_in[3];
    const void* Wr0 = d_in[4];  const void* br0 = d_in[5];
    const void* att0  = d_in[6];  const void* bias0 = d_in[7];
    const void* Wl1 = d_in[8];  const void* bl1 = d_in[9];
    const void* Wr1 = d_in[10]; const void* br1 = d_in[11];
    const void* att1  = d_in[12]; const void* bias1 = d_in[13];
    const void* Wl2 = d_in[14]; const void* bl2 = d_in[15];
    const void* Wr2 = d_in[16]; const void* br2 = d_in[17];
    const void* att2  = d_in[18]; const void* bias2 = d_in[19];

    // workspace layout (~59.9 MB), f32-slot offsets
    float* ws = (float*)d_ws;
    __hip_bfloat16* hbuf = (__hip_bfloat16*)ws;                  // [N,64] bf16
    __hip_bfloat16* xl2  = (__hip_bfloat16*)(ws + 1600000);      // [N,256] bf16
    __hip_bfloat16* xr2  = (__hip_bfloat16*)(ws + 8000000);      // [N,256] bf16
    __hip_bfloat16* xl   = xl2;                                  // [N,64] alias (layers 0/1)
    __hip_bfloat16* xr   = (__hip_bfloat16*)(ws + 4800000);      // [N,64] alias
    int* csr    = (int*)(ws + 14400000);                         // 450k
    int* offs   = csr + 450000;                                  // 50001
    int* counts = offs + 50004;                                  // 50k (doubles as fill cursor)
    int* bsum   = counts + 50000;
    int* bpre   = bsum + 256;
    int* flag   = bpre + 256;
    __hip_bfloat16* wt = (__hip_bfloat16*)(flag + 4);            // 49152 bf16 panels (96 KB)

    const int NGE = cdiv(N_ETOT, 256);
    const int NGW = cdiv(N_NODES, 4);
    const int NGM = cdiv(N_NODES, 64);

    // ---- prep: dtype flag + counts zero, weight transpose ----
    detect_zero_kernel<<<SCAN_BLOCKS, 256, 0, stream>>>(x, flag, counts);
    prep_w_kernel<<<192, 256, 0, stream>>>(Wl0, Wr0, Wl1, Wr1, Wl2, Wr2, wt, flag);

    // ---- CSR build ----
    count_kernel<<<NGE, 256, 0, stream>>>(ei, counts);
    scan_phase1<<<SCAN_BLOCKS, 256, 0, stream>>>(counts, bsum);
    scan_phase2<<<1, 256, 0, stream>>>(bsum, bpre, offs);
    scan_phase3<<<SCAN_BLOCKS, 256, 0, stream>>>(counts, bpre, offs);
    fill_kernel<<<NGE, 256, 0, stream>>>(ei, counts, csr);

    // ---- layer 0 ----
    lin_mfma_kernel<1, true><<<dim3(NGM, 2), 256, 0, stream>>>(
        x, wt, 0, 4096, bl0, br0, xl, xr, flag);
    gat_fused16_kernel<<<NGW, 256, 0, stream>>>(csr, offs, xl, xr, att0, bias0, hbuf, flag);

    // ---- layer 1 ----
    lin_mfma_kernel<1, false><<<dim3(NGM, 2), 256, 0, stream>>>(
        hbuf, wt, 8192, 12288, bl1, br1, xl, xr, flag);
    gat_fused16_kernel<<<NGW, 256, 0, stream>>>(csr, offs, xl, xr, att1, bias1, hbuf, flag);

    // ---- layer 2: MFMA linear, then one all-heads pass ----
    lin_mfma_kernel<4, false><<<dim3(NGM, 8), 256, 0, stream>>>(
        hbuf, wt, 16384, 32768, bl2, br2, xl2, xr2, flag);
    gat256_kernel<<<NGW, 256, 0, stream>>>(csr, offs, xl2, xr2, att2, bias2, d_out, flag);
}